// Round 6
// baseline (371.703 us; speedup 1.0000x reference)
//
#include <hip/hip_runtime.h>

#define WG 256
#define BN 128        // nodes per bucket
#define NBMAX 800     // max buckets (N <= 102400)
#define CHUNK 8192    // edges per binning chunk

typedef unsigned int uint32;

__device__ inline ushort f2bf(float f) {  // fp32 -> bf16 RNE
  uint32 u = __float_as_uint(f);
  return (ushort)((u + 0x7fffu + ((u >> 16) & 1u)) >> 16);
}
__device__ inline float bflo(uint32 v) { return __uint_as_float(v << 16); }
__device__ inline float bfhi(uint32 v) { return __uint_as_float(v & 0xffff0000u); }

// int64 layout <=> all odd 32-bit words of the first 8 entries are zero.
// (int32 random indices in [0,1e5): P(8 zeros) ~ 1e-40.) Uniform across
// threads/blocks -> no sync needed, branch is wave-uniform.
__device__ inline bool detect_i64(const uint32* ei) {
  uint32 acc = 0;
#pragma unroll
  for (int i = 0; i < 8; i++) acc |= ei[2 * i + 1];
  return acc == 0u;
}

// ---------------------------------------------------------------------------
// Per-chunk bucket histogram (LDS atomics only): hist[chunk][NB]
// ---------------------------------------------------------------------------
__global__ __launch_bounds__(WG) void k_hist(const int* __restrict__ ei,
                                             int* __restrict__ hist, int NB, int E) {
  __shared__ int hc[NBMAX];
  const int c = blockIdx.x;
  for (int b = threadIdx.x; b < NB; b += WG) hc[b] = 0;
  __syncthreads();
  const bool i64 = detect_i64((const uint32*)ei);
  const int e0 = c * CHUNK;
  for (int i = 0; i < CHUNK; i += WG) {
    int e = e0 + i + threadIdx.x;
    if (e < E) {
      int d = i64 ? ei[2 * (E + e)] : ei[E + e];
      atomicAdd(&hc[d / BN], 1);
    }
  }
  __syncthreads();
  for (int b = threadIdx.x; b < NB; b += WG) hist[(size_t)c * NB + b] = hc[b];
}

// ---------------------------------------------------------------------------
// Per-bucket exclusive scan over chunks (in place); total -> bucketTotal[b]
// ---------------------------------------------------------------------------
__global__ __launch_bounds__(512) void k_bscan1(int* __restrict__ hist,
                                                int* __restrict__ bucketTotal,
                                                int NB, int NC) {
  __shared__ int sh[512];
  const int b = blockIdx.x;
  int carry = 0;
  for (int c0 = 0; c0 < NC; c0 += 512) {
    int c = c0 + (int)threadIdx.x;
    int v = (c < NC) ? hist[(size_t)c * NB + b] : 0;
    sh[threadIdx.x] = v;
    __syncthreads();
    for (int off = 1; off < 512; off <<= 1) {
      int t = (threadIdx.x >= (unsigned)off) ? sh[threadIdx.x - off] : 0;
      __syncthreads();
      sh[threadIdx.x] += t;
      __syncthreads();
    }
    if (c < NC) hist[(size_t)c * NB + b] = carry + sh[threadIdx.x] - v;
    carry += sh[511];
    __syncthreads();
  }
  if (threadIdx.x == 0) bucketTotal[b] = carry;
}

// exclusive scan of bucketTotal -> bucketBase[0..NB]
__global__ __launch_bounds__(1024) void k_bbase(const int* __restrict__ bucketTotal,
                                                int* __restrict__ bucketBase, int NB) {
  __shared__ int sh[1024];
  int carry = 0;
  for (int b0 = 0; b0 < NB; b0 += 1024) {
    int b = b0 + (int)threadIdx.x;
    int v = (b < NB) ? bucketTotal[b] : 0;
    sh[threadIdx.x] = v;
    __syncthreads();
    for (int off = 1; off < 1024; off <<= 1) {
      int t = (threadIdx.x >= (unsigned)off) ? sh[threadIdx.x - off] : 0;
      __syncthreads();
      sh[threadIdx.x] += t;
      __syncthreads();
    }
    if (b < NB) bucketBase[b] = carry + sh[threadIdx.x] - v;
    carry += sh[1023];
    __syncthreads();
  }
  if (threadIdx.x == 0) bucketBase[NB] = carry;
}

// ---------------------------------------------------------------------------
// Multisplit scatter: chunk c writes packed (src<<7 | dst%BN) into its
// private slice of each bucket region. LDS cursors; no global atomics.
// ---------------------------------------------------------------------------
__global__ __launch_bounds__(WG) void k_mscatter(const int* __restrict__ ei,
                                                 const int* __restrict__ hist,
                                                 const int* __restrict__ bucketBase,
                                                 uint32* __restrict__ pairs,
                                                 int NB, int E) {
  __shared__ int cur[NBMAX];
  const int c = blockIdx.x;
  for (int b = threadIdx.x; b < NB; b += WG)
    cur[b] = bucketBase[b] + hist[(size_t)c * NB + b];
  __syncthreads();
  const bool i64 = detect_i64((const uint32*)ei);
  const int e0 = c * CHUNK;
  for (int i = 0; i < CHUNK; i += WG) {
    int e = e0 + i + threadIdx.x;
    if (e < E) {
      int s, d;
      if (i64) { s = ei[2 * e]; d = ei[2 * (E + e)]; }
      else     { s = ei[e];     d = ei[E + e]; }
      int pos = atomicAdd(&cur[d / BN], 1);
      pairs[pos] = ((uint32)s << 7) | (uint32)(d & (BN - 1));
    }
  }
}

// ---------------------------------------------------------------------------
// Per-bucket counting sort: packed pairs -> perm, rowptr, dinv.
// ---------------------------------------------------------------------------
__global__ __launch_bounds__(WG) void k_bsort(const uint32* __restrict__ pairs,
                                              const int* __restrict__ bucketBase,
                                              int* __restrict__ perm,
                                              int* __restrict__ rowptr,
                                              float* __restrict__ dinv,
                                              int N, int NB) {
  __shared__ int cnt[BN];
  __shared__ int cur[BN];
  __shared__ int sc[BN];
  const int b = blockIdx.x;
  const int t = threadIdx.x;
  if (t < BN) cnt[t] = 0;
  __syncthreads();
  const int beg = bucketBase[b], end = bucketBase[b + 1];
  for (int e = beg + t; e < end; e += WG)
    atomicAdd(&cnt[pairs[e] & (BN - 1)], 1);
  __syncthreads();
  if (t < BN) sc[t] = cnt[t];
  __syncthreads();
  for (int off = 1; off < BN; off <<= 1) {
    int v = (t < BN && t >= off) ? sc[t - off] : 0;
    __syncthreads();
    if (t < BN) sc[t] += v;
    __syncthreads();
  }
  if (t < BN) {
    int excl = beg + sc[t] - cnt[t];
    cur[t] = excl;
    int n = b * BN + t;
    if (n < N) {
      rowptr[n] = excl;
      dinv[n] = rsqrtf((float)(cnt[t] + 1));  // +1 = self-loop
    }
  }
  if (b == NB - 1 && t == 0) rowptr[N] = end;
  __syncthreads();
  for (int e = beg + t; e < end; e += WG) {
    uint32 p = pairs[e];
    int pos = atomicAdd(&cur[p & (BN - 1)], 1);
    perm[pos] = (int)(p >> 7);
  }
}

// ---------------------------------------------------------------------------
// GEMM1: ht1g[g][n][8u32] = bf16( (x[n][128] @ W1[128][64]) * dinv[n] ),
// channel-group-major (g = ch/16) so the aggregation gather table per group
// is N*16*2B = 3.2MB (fits per-XCD L2).
// ---------------------------------------------------------------------------
__global__ __launch_bounds__(WG) void k_gemm1(const float* __restrict__ x,
                                              const float* __restrict__ W1,
                                              const float* __restrict__ dinv,
                                              uint32* __restrict__ ht1g, int N) {
  __shared__ float xs[64 * 128];
  __shared__ float w1s[128 * 64];
  const int tid = threadIdx.x;
  const int n0 = blockIdx.x * 64;

  for (int v = tid; v < 2048; v += WG)
    *(float4*)&w1s[v * 4] = ((const float4*)W1)[v];
  for (int v = tid; v < 2048; v += WG) {
    int row = v >> 5, c4 = v & 31;
    int n = n0 + row;
    float4 val = make_float4(0.f, 0.f, 0.f, 0.f);
    if (n < N) val = ((const float4*)x)[(size_t)n * 32 + c4];
    *(float4*)&xs[row * 128 + ((c4 ^ ((row >> 2) & 3)) << 2)] = val;
  }
  __syncthreads();

  const int cg = tid & 15;   // channel quad: ch 4cg..4cg+3
  const int ng = tid >> 4;
  const int ngm = ng & 3;
  float acc[4][4] = {};

#pragma unroll 4
  for (int k4 = 0; k4 < 32; k4++) {
    float4 xa[4], wv[4];
#pragma unroll
    for (int i = 0; i < 4; i++)
      xa[i] = *(const float4*)&xs[(ng * 4 + i) * 128 + ((k4 ^ ngm) << 2)];
#pragma unroll
    for (int kk = 0; kk < 4; kk++)
      wv[kk] = *(const float4*)&w1s[(k4 * 4 + kk) * 64 + cg * 4];
#pragma unroll
    for (int i = 0; i < 4; i++) {
#pragma unroll
      for (int kk = 0; kk < 4; kk++) {
        float a = (kk == 0) ? xa[i].x : (kk == 1) ? xa[i].y : (kk == 2) ? xa[i].z : xa[i].w;
        acc[i][0] += a * wv[kk].x;
        acc[i][1] += a * wv[kk].y;
        acc[i][2] += a * wv[kk].z;
        acc[i][3] += a * wv[kk].w;
      }
    }
  }

#pragma unroll
  for (int i = 0; i < 4; i++) {
    int n = n0 + ng * 4 + i;
    if (n >= N) continue;
    float dv = dinv[n];
    uint32 u01 = ((uint32)f2bf(acc[i][1] * dv) << 16) | f2bf(acc[i][0] * dv);
    uint32 u23 = ((uint32)f2bf(acc[i][3] * dv) << 16) | f2bf(acc[i][2] * dv);
    // group g = cg>>2, u32 slots (cg&3)*2, +1
    ((uint2*)ht1g)[((size_t)(cg >> 2) * N + n) * 4 + (cg & 3)] = make_uint2(u01, u23);
  }
}

// ---------------------------------------------------------------------------
// Channel-group-split CSR aggregation (shared by both layers).
// Grid = NG * nodeBlocks, group-major: blocks of one group run together so
// the group's 3.2MB table stays L2-resident per XCD.
// Wave per node: 8 edge-slots x 8 lanes (32B/edge), 16-edge unroll,
// xor-shuffle reduce over slots. aggs layout [g][n][16 f32].
// ---------------------------------------------------------------------------
__global__ __launch_bounds__(WG) void k_aggs(const int* __restrict__ rowptr,
                                             const int* __restrict__ perm,
                                             const float* __restrict__ dinv,
                                             const uint32* __restrict__ htg,
                                             float* __restrict__ aggs,
                                             int N, int nodeBlocks) {
  const int g = blockIdx.x / nodeBlocks;
  const int nb = blockIdx.x % nodeBlocks;
  const int n = nb * 4 + (threadIdx.x >> 6);
  const int lane = threadIdx.x & 63;
  if (n >= N) return;
  const int slot = lane >> 3;   // edge slot 0..7
  const int q = lane & 7;       // u32 within 32B row (2 ch)
  const uint32* __restrict__ tab = htg + (size_t)g * N * 8;
  int beg = rowptr[n], end = rowptr[n + 1];
  float a0 = 0.f, a1 = 0.f;
  if (slot == 0) {  // self-loop term
    uint32 v = tab[(size_t)n * 8 + q];
    a0 += bflo(v); a1 += bfhi(v);
  }
  int j = beg;
  for (; j + 16 <= end; j += 16) {
    int s0 = perm[j + slot];
    int s1 = perm[j + 8 + slot];
    uint32 v0 = tab[(size_t)s0 * 8 + q];
    uint32 v1 = tab[(size_t)s1 * 8 + q];
    a0 += bflo(v0) + bflo(v1);
    a1 += bfhi(v0) + bfhi(v1);
  }
  for (; j + 8 <= end; j += 8) {
    int s = perm[j + slot];
    uint32 v = tab[(size_t)s * 8 + q];
    a0 += bflo(v); a1 += bfhi(v);
  }
  if (j + slot < end) {
    int s = perm[j + slot];
    uint32 v = tab[(size_t)s * 8 + q];
    a0 += bflo(v); a1 += bfhi(v);
  }
  a0 += __shfl_xor(a0, 8, 64);
  a1 += __shfl_xor(a1, 8, 64);
  a0 += __shfl_xor(a0, 16, 64);
  a1 += __shfl_xor(a1, 16, 64);
  a0 += __shfl_xor(a0, 32, 64);
  a1 += __shfl_xor(a1, 32, 64);
  if (slot == 0) {
    float dv = dinv[n];
    ((float2*)aggs)[((size_t)g * N + n) * 8 + q] = make_float2(a0 * dv, a1 * dv);
  }
}

// ---------------------------------------------------------------------------
// GEMM2: ht2g[g][n][8u32] = bf16( (relu(agg1+b1) @ W2[64][32]) * dinv[n] )
// agg1 input in [4][N][16] group-split layout; ht2g in 2 groups of 16ch.
// ---------------------------------------------------------------------------
__global__ __launch_bounds__(WG) void k_gemm2(const float* __restrict__ agg1,
                                              const float* __restrict__ b1,
                                              const float* __restrict__ W2,
                                              const float* __restrict__ dinv,
                                              uint32* __restrict__ ht2g, int N) {
  __shared__ float as[64 * 68];
  __shared__ float w2s[64 * 32];
  const int tid = threadIdx.x;
  const int n0 = blockIdx.x * 64;

  for (int v = tid; v < 512; v += WG)
    *(float4*)&w2s[v * 4] = ((const float4*)W2)[v];
  for (int v = tid; v < 1024; v += WG) {
    int row = v >> 4, c4 = v & 15;   // c4 = channel quad (ch 4c4..4c4+3)
    int n = n0 + row;
    float4 val = make_float4(0.f, 0.f, 0.f, 0.f);
    if (n < N) {
      float4 g = ((const float4*)agg1)[((size_t)(c4 >> 2) * N + n) * 4 + (c4 & 3)];
      float4 bb = ((const float4*)b1)[c4];
      val.x = fmaxf(g.x + bb.x, 0.f);
      val.y = fmaxf(g.y + bb.y, 0.f);
      val.z = fmaxf(g.z + bb.z, 0.f);
      val.w = fmaxf(g.w + bb.w, 0.f);
    }
    *(float4*)&as[row * 68 + c4 * 4] = val;
  }
  __syncthreads();

  const int cg = tid & 15;   // channel pair: ch 2cg, 2cg+1
  const int ng = tid >> 4;
  float acc[4][2] = {};

#pragma unroll 4
  for (int k4 = 0; k4 < 16; k4++) {
    float4 xa[4];
    float2 wv[4];
#pragma unroll
    for (int i = 0; i < 4; i++)
      xa[i] = *(const float4*)&as[(ng * 4 + i) * 68 + k4 * 4];
#pragma unroll
    for (int kk = 0; kk < 4; kk++)
      wv[kk] = *(const float2*)&w2s[(k4 * 4 + kk) * 32 + cg * 2];
#pragma unroll
    for (int i = 0; i < 4; i++) {
#pragma unroll
      for (int kk = 0; kk < 4; kk++) {
        float a = (kk == 0) ? xa[i].x : (kk == 1) ? xa[i].y : (kk == 2) ? xa[i].z : xa[i].w;
        acc[i][0] += a * wv[kk].x;
        acc[i][1] += a * wv[kk].y;
      }
    }
  }

#pragma unroll
  for (int i = 0; i < 4; i++) {
    int n = n0 + ng * 4 + i;
    if (n >= N) continue;
    float dv = dinv[n];
    // group g = cg>>3 (16ch groups), u32 slot cg&7
    ht2g[((size_t)(cg >> 3) * N + n) * 8 + (cg & 7)] =
        ((uint32)f2bf(acc[i][1] * dv) << 16) | f2bf(acc[i][0] * dv);
  }
}

// ---------------------------------------------------------------------------
// Final head: out[n][2] = (relu(relu(agg2[n]+b2) @ fc_w + fc_b)) @ out_w + out_b
// agg2 input in [2][N][16] group-split layout.
// ---------------------------------------------------------------------------
__global__ __launch_bounds__(WG) void k_final(const float* __restrict__ agg2,
                                              const float* __restrict__ b2,
                                              const float* __restrict__ fc_w,
                                              const float* __restrict__ fc_b,
                                              const float* __restrict__ out_w,
                                              const float* __restrict__ out_b,
                                              float* __restrict__ out, int N) {
  __shared__ float hs[256 * 33];
  __shared__ float fcs[32 * 32];
  __shared__ float b2s[32], fcbs[32], ows[64];
  const int tid = threadIdx.x;
  const int n0 = blockIdx.x * 256;

  ((float4*)fcs)[tid] = ((const float4*)fc_w)[tid];
  if (tid < 32) {
    b2s[tid] = b2[tid];
    fcbs[tid] = fc_b[tid];
  }
  if (tid < 64) ows[tid] = out_w[tid];
  for (int v = tid; v < 2048; v += WG) {
    int row = v >> 3, c4 = v & 7;   // ch quad
    int n = n0 + row;
    float4 val = make_float4(0.f, 0.f, 0.f, 0.f);
    if (n < N)
      val = ((const float4*)agg2)[((size_t)(c4 >> 2) * N + n) * 4 + (c4 & 3)];
    float* p = &hs[row * 33 + c4 * 4];
    p[0] = val.x; p[1] = val.y; p[2] = val.z; p[3] = val.w;
  }
  __syncthreads();

  int n = n0 + tid;
  float acc[32] = {};
  const int base = tid * 33;
#pragma unroll
  for (int k = 0; k < 32; k++) {
    float vk = fmaxf(hs[base + k] + b2s[k], 0.f);
#pragma unroll
    for (int j4 = 0; j4 < 8; j4++) {
      float4 f = *(const float4*)&fcs[k * 32 + j4 * 4];
      acc[j4 * 4 + 0] += vk * f.x;
      acc[j4 * 4 + 1] += vk * f.y;
      acc[j4 * 4 + 2] += vk * f.z;
      acc[j4 * 4 + 3] += vk * f.w;
    }
  }
  float o0 = out_b[0], o1 = out_b[1];
#pragma unroll
  for (int j = 0; j < 32; j++) {
    float t = fmaxf(acc[j] + fcbs[j], 0.f);
    o0 += t * ows[2 * j];
    o1 += t * ows[2 * j + 1];
  }
  if (n < N) ((float2*)out)[n] = make_float2(o0, o1);
}

// ---------------------------------------------------------------------------
extern "C" void kernel_launch(void* const* d_in, const int* in_sizes, int n_in,
                              void* d_out, int out_size, void* d_ws, size_t ws_size,
                              hipStream_t stream) {
  const float* x   = (const float*)d_in[0];
  const int*   ei  = (const int*)d_in[1];
  const float* W1  = (const float*)d_in[2];
  const float* b1  = (const float*)d_in[3];
  const float* W2  = (const float*)d_in[4];
  const float* b2  = (const float*)d_in[5];
  const float* fcw = (const float*)d_in[6];
  const float* fcb = (const float*)d_in[7];
  const float* ow  = (const float*)d_in[8];
  const float* ob  = (const float*)d_in[9];

  const int N  = in_sizes[0] / 128;
  const int E  = in_sizes[1] / 2;
  const int NB = (N + BN - 1) / BN;        // buckets (<= NBMAX)
  const int NC = (E + CHUNK - 1) / CHUNK;  // chunks
  const int nodeBlocks = (N + 3) / 4;      // 4 node-waves per 256-thread block

  // workspace: pairs(E) | perm(E) | rowptr(N+4) | dinv(N) | bucketTotal/Base
  // | hist(NC*NB) | ht1g(32N u32) | agg1(64N f) | ht2g(16N u32) | agg2(32N f)
  char* p = (char*)d_ws;
  uint32* pairs = (uint32*)p;        p += (size_t)E * 4 + 64;
  int* perm = (int*)p;               p += (size_t)E * 4 + 64;
  int* rowptr = (int*)p;             p += ((size_t)N + 4) * 4;
  float* dinv = (float*)p;           p += (size_t)N * 4 + 64;
  int* bucketTotal = (int*)p;        p += ((size_t)NB + 16) * 4;
  int* bucketBase = (int*)p;         p += ((size_t)NB + 17) * 4;
  p = (char*)(((uintptr_t)p + 63) & ~(uintptr_t)63);
  int* hist = (int*)p;               p += (size_t)NC * NB * 4 + 64;
  p = (char*)(((uintptr_t)p + 63) & ~(uintptr_t)63);
  uint32* ht1g = (uint32*)p;         p += (size_t)N * 32 * 4;
  float* agg1 = (float*)p;           p += (size_t)N * 64 * 4;
  uint32* ht2g = (uint32*)p;         p += (size_t)N * 16 * 4;
  float* agg2 = (float*)p;           p += (size_t)N * 32 * 4;
  float* out = (float*)d_out;

  hipLaunchKernelGGL(k_hist, dim3(NC), dim3(WG), 0, stream,
                     ei, hist, NB, E);
  hipLaunchKernelGGL(k_bscan1, dim3(NB), dim3(512), 0, stream,
                     hist, bucketTotal, NB, NC);
  hipLaunchKernelGGL(k_bbase, dim3(1), dim3(1024), 0, stream,
                     bucketTotal, bucketBase, NB);
  hipLaunchKernelGGL(k_mscatter, dim3(NC), dim3(WG), 0, stream,
                     ei, hist, bucketBase, pairs, NB, E);
  hipLaunchKernelGGL(k_bsort, dim3(NB), dim3(WG), 0, stream,
                     pairs, bucketBase, perm, rowptr, dinv, N, NB);
  hipLaunchKernelGGL(k_gemm1, dim3((N + 63) / 64), dim3(WG), 0, stream,
                     x, W1, dinv, ht1g, N);
  hipLaunchKernelGGL(k_aggs, dim3(4 * nodeBlocks), dim3(WG), 0, stream,
                     rowptr, perm, dinv, ht1g, agg1, N, nodeBlocks);
  hipLaunchKernelGGL(k_gemm2, dim3((N + 63) / 64), dim3(WG), 0, stream,
                     agg1, b1, W2, dinv, ht2g, N);
  hipLaunchKernelGGL(k_aggs, dim3(2 * nodeBlocks), dim3(WG), 0, stream,
                     rowptr, perm, dinv, ht2g, agg2, N, nodeBlocks);
  hipLaunchKernelGGL(k_final, dim3((N + 255) / 256), dim3(WG), 0, stream,
                     agg2, b2, fcw, fcb, ow, ob, out, N);
}

// Round 7
// 318.565 us; speedup vs baseline: 1.1668x; 1.1668x over previous
//
#include <hip/hip_runtime.h>

#define WG 256
#define BN 128        // nodes per bucket
#define NBMAX 800     // max buckets (N <= 102400)
#define CHUNK 8192    // edges per binning chunk

typedef unsigned int uint32;

__device__ inline ushort f2bf(float f) {  // fp32 -> bf16 RNE
  uint32 u = __float_as_uint(f);
  return (ushort)((u + 0x7fffu + ((u >> 16) & 1u)) >> 16);
}
__device__ inline float bflo(uint32 v) { return __uint_as_float(v << 16); }
__device__ inline float bfhi(uint32 v) { return __uint_as_float(v & 0xffff0000u); }

// int64 layout <=> all odd 32-bit words of the first 8 entries are zero.
__device__ inline bool detect_i64(const uint32* ei) {
  uint32 acc = 0;
#pragma unroll
  for (int i = 0; i < 8; i++) acc |= ei[2 * i + 1];
  return acc == 0u;
}

// ---------------------------------------------------------------------------
// Single-pass binning: per-chunk LDS histogram -> one global atomicAdd per
// (chunk,bucket) reserves a private slice inside the bucket's fixed-capacity
// region [b*CAP, (b+1)*CAP) -> scatter packed (src<<7 | dst%BN).
// cursor[] must be zeroed beforehand; after this kernel cursor[b] = bucket
// edge count. Chunk edge data is re-read from L2 on the scatter pass.
// ---------------------------------------------------------------------------
__global__ __launch_bounds__(WG) void k_bin(const int* __restrict__ ei,
                                            int* __restrict__ cursor,
                                            uint32* __restrict__ pairs,
                                            int NB, int E, int CAP) {
  __shared__ int hc[NBMAX];
  __shared__ int curs[NBMAX];
  const int c = blockIdx.x;
  for (int b = threadIdx.x; b < NB; b += WG) hc[b] = 0;
  __syncthreads();
  const bool i64 = detect_i64((const uint32*)ei);
  const int e0 = c * CHUNK;
  for (int i = 0; i < CHUNK; i += WG) {
    int e = e0 + i + threadIdx.x;
    if (e < E) {
      int d = i64 ? ei[2 * (E + e)] : ei[E + e];
      atomicAdd(&hc[d / BN], 1);
    }
  }
  __syncthreads();
  for (int b = threadIdx.x; b < NB; b += WG) {
    int cnt = hc[b];
    int base = 0;
    if (cnt > 0) base = atomicAdd(&cursor[b], cnt);
    curs[b] = b * CAP + base;
  }
  __syncthreads();
  for (int i = 0; i < CHUNK; i += WG) {
    int e = e0 + i + threadIdx.x;
    if (e < E) {
      int s, d;
      if (i64) { s = ei[2 * e]; d = ei[2 * (E + e)]; }
      else     { s = ei[e];     d = ei[E + e]; }
      int b = d / BN;
      int pos = atomicAdd(&curs[b], 1);
      if (pos < (b + 1) * CAP)  // overflow guard (never triggers w/ margin)
        pairs[pos] = ((uint32)s << 7) | (uint32)(d & (BN - 1));
    }
  }
}

// ---------------------------------------------------------------------------
// Per-bucket counting sort: packed pairs -> perm (grouped per dst node),
// rowbeg/rowend, dinv. Cursors in LDS; writes contiguous per block.
// ---------------------------------------------------------------------------
__global__ __launch_bounds__(WG) void k_bsort(const uint32* __restrict__ pairs,
                                              const int* __restrict__ cursor,
                                              int* __restrict__ perm,
                                              int* __restrict__ rowbeg,
                                              int* __restrict__ rowend,
                                              float* __restrict__ dinv,
                                              int N, int CAP) {
  __shared__ int cnt[BN];
  __shared__ int cur[BN];
  __shared__ int sc[BN];
  const int b = blockIdx.x;
  const int t = threadIdx.x;
  if (t < BN) cnt[t] = 0;
  __syncthreads();
  const int beg = b * CAP;
  int cb = cursor[b];
  const int end = beg + (cb < CAP ? cb : CAP);
  for (int e = beg + t; e < end; e += WG)
    atomicAdd(&cnt[pairs[e] & (BN - 1)], 1);
  __syncthreads();
  if (t < BN) sc[t] = cnt[t];
  __syncthreads();
  for (int off = 1; off < BN; off <<= 1) {
    int v = (t < BN && t >= off) ? sc[t - off] : 0;
    __syncthreads();
    if (t < BN) sc[t] += v;
    __syncthreads();
  }
  if (t < BN) {
    int excl = beg + sc[t] - cnt[t];
    cur[t] = excl;
    int n = b * BN + t;
    if (n < N) {
      rowbeg[n] = excl;
      rowend[n] = excl + cnt[t];
      dinv[n] = rsqrtf((float)(cnt[t] + 1));  // +1 = self-loop
    }
  }
  __syncthreads();
  for (int e = beg + t; e < end; e += WG) {
    uint32 p = pairs[e];
    int pos = atomicAdd(&cur[p & (BN - 1)], 1);
    perm[pos] = (int)(p >> 7);
  }
}

// ---------------------------------------------------------------------------
// GEMM1: ht1[n][64] = bf16( (x[n][128] @ W1[128][64]) * dinv[n] )
// ---------------------------------------------------------------------------
__global__ __launch_bounds__(WG) void k_gemm1(const float* __restrict__ x,
                                              const float* __restrict__ W1,
                                              const float* __restrict__ dinv,
                                              uint32* __restrict__ ht1, int N) {
  __shared__ float xs[64 * 128];
  __shared__ float w1s[128 * 64];
  const int tid = threadIdx.x;
  const int n0 = blockIdx.x * 64;

  for (int v = tid; v < 2048; v += WG)
    *(float4*)&w1s[v * 4] = ((const float4*)W1)[v];
  for (int v = tid; v < 2048; v += WG) {
    int row = v >> 5, c4 = v & 31;
    int n = n0 + row;
    float4 val = make_float4(0.f, 0.f, 0.f, 0.f);
    if (n < N) val = ((const float4*)x)[(size_t)n * 32 + c4];
    *(float4*)&xs[row * 128 + ((c4 ^ ((row >> 2) & 3)) << 2)] = val;
  }
  __syncthreads();

  const int cg = tid & 15;
  const int ng = tid >> 4;
  const int ngm = ng & 3;
  float acc[4][4] = {};

#pragma unroll 4
  for (int k4 = 0; k4 < 32; k4++) {
    float4 xa[4], wv[4];
#pragma unroll
    for (int i = 0; i < 4; i++)
      xa[i] = *(const float4*)&xs[(ng * 4 + i) * 128 + ((k4 ^ ngm) << 2)];
#pragma unroll
    for (int kk = 0; kk < 4; kk++)
      wv[kk] = *(const float4*)&w1s[(k4 * 4 + kk) * 64 + cg * 4];
#pragma unroll
    for (int i = 0; i < 4; i++) {
#pragma unroll
      for (int kk = 0; kk < 4; kk++) {
        float a = (kk == 0) ? xa[i].x : (kk == 1) ? xa[i].y : (kk == 2) ? xa[i].z : xa[i].w;
        acc[i][0] += a * wv[kk].x;
        acc[i][1] += a * wv[kk].y;
        acc[i][2] += a * wv[kk].z;
        acc[i][3] += a * wv[kk].w;
      }
    }
  }

#pragma unroll
  for (int i = 0; i < 4; i++) {
    int n = n0 + ng * 4 + i;
    if (n >= N) continue;
    float dv = dinv[n];
    uint32 u01 = ((uint32)f2bf(acc[i][1] * dv) << 16) | f2bf(acc[i][0] * dv);
    uint32 u23 = ((uint32)f2bf(acc[i][3] * dv) << 16) | f2bf(acc[i][2] * dv);
    ((uint2*)ht1)[(size_t)n * 16 + cg] = make_uint2(u01, u23);
  }
}

// ---------------------------------------------------------------------------
// CSR aggregation, 64 ch bf16: wave per node; 2 edges per step; 16-edge
// unroll (8 perm + 8 table loads in flight); fp32 accumulate.
// ---------------------------------------------------------------------------
__global__ __launch_bounds__(WG) void k_agg64b(const int* __restrict__ rowbeg,
                                               const int* __restrict__ rowend,
                                               const int* __restrict__ perm,
                                               const float* __restrict__ dinv,
                                               const uint32* __restrict__ ht,
                                               float* __restrict__ agg, int N) {
  int n = (blockIdx.x * WG + threadIdx.x) >> 6;
  int lane = threadIdx.x & 63;
  if (n >= N) return;
  const int sub = lane >> 5;   // which edge of the pair
  const int cp = lane & 31;    // channel-pair (2 ch per lane)
  int beg = rowbeg[n], end = rowend[n];
  float a0 = 0.f, a1 = 0.f;
  if (sub == 0) {  // self-loop term
    uint32 v = ht[(size_t)n * 32 + cp];
    a0 += bflo(v); a1 += bfhi(v);
  }
  int j = beg;
  for (; j + 16 <= end; j += 16) {  // 16 edges per iteration
    int s[8];
    uint32 v[8];
#pragma unroll
    for (int u = 0; u < 8; u++) s[u] = perm[j + 2 * u + sub];
#pragma unroll
    for (int u = 0; u < 8; u++) v[u] = ht[(size_t)s[u] * 32 + cp];
#pragma unroll
    for (int u = 0; u < 8; u++) { a0 += bflo(v[u]); a1 += bfhi(v[u]); }
  }
  for (; j + 2 <= end; j += 2) {
    int s = perm[j + sub];
    uint32 v = ht[(size_t)s * 32 + cp];
    a0 += bflo(v); a1 += bfhi(v);
  }
  if (j < end && sub == 0) {  // odd remainder
    int s = perm[j];
    uint32 v = ht[(size_t)s * 32 + cp];
    a0 += bflo(v); a1 += bfhi(v);
  }
  a0 += __shfl_xor(a0, 32, 64);
  a1 += __shfl_xor(a1, 32, 64);
  if (sub == 0) {
    float dv = dinv[n];
    ((float2*)agg)[(size_t)n * 32 + cp] = make_float2(a0 * dv, a1 * dv);
  }
}

// ---------------------------------------------------------------------------
// GEMM2: ht2[n][32] = bf16( (relu(agg1[n][64] + b1) @ W2[64][32]) * dinv[n] )
// ---------------------------------------------------------------------------
__global__ __launch_bounds__(WG) void k_gemm2(const float* __restrict__ agg1,
                                              const float* __restrict__ b1,
                                              const float* __restrict__ W2,
                                              const float* __restrict__ dinv,
                                              uint32* __restrict__ ht2, int N) {
  __shared__ float as[64 * 68];
  __shared__ float w2s[64 * 32];
  const int tid = threadIdx.x;
  const int n0 = blockIdx.x * 64;

  for (int v = tid; v < 512; v += WG)
    *(float4*)&w2s[v * 4] = ((const float4*)W2)[v];
  for (int v = tid; v < 1024; v += WG) {
    int row = v >> 4, c4 = v & 15;
    int n = n0 + row;
    float4 val = make_float4(0.f, 0.f, 0.f, 0.f);
    if (n < N) {
      float4 g = ((const float4*)agg1)[(size_t)n * 16 + c4];
      float4 bb = ((const float4*)b1)[c4];
      val.x = fmaxf(g.x + bb.x, 0.f);
      val.y = fmaxf(g.y + bb.y, 0.f);
      val.z = fmaxf(g.z + bb.z, 0.f);
      val.w = fmaxf(g.w + bb.w, 0.f);
    }
    *(float4*)&as[row * 68 + c4 * 4] = val;
  }
  __syncthreads();

  const int cg = tid & 15;
  const int ng = tid >> 4;
  float acc[4][2] = {};

#pragma unroll 4
  for (int k4 = 0; k4 < 16; k4++) {
    float4 xa[4];
    float2 wv[4];
#pragma unroll
    for (int i = 0; i < 4; i++)
      xa[i] = *(const float4*)&as[(ng * 4 + i) * 68 + k4 * 4];
#pragma unroll
    for (int kk = 0; kk < 4; kk++)
      wv[kk] = *(const float2*)&w2s[(k4 * 4 + kk) * 32 + cg * 2];
#pragma unroll
    for (int i = 0; i < 4; i++) {
#pragma unroll
      for (int kk = 0; kk < 4; kk++) {
        float a = (kk == 0) ? xa[i].x : (kk == 1) ? xa[i].y : (kk == 2) ? xa[i].z : xa[i].w;
        acc[i][0] += a * wv[kk].x;
        acc[i][1] += a * wv[kk].y;
      }
    }
  }

#pragma unroll
  for (int i = 0; i < 4; i++) {
    int n = n0 + ng * 4 + i;
    if (n >= N) continue;
    float dv = dinv[n];
    ht2[(size_t)n * 16 + cg] =
        ((uint32)f2bf(acc[i][1] * dv) << 16) | f2bf(acc[i][0] * dv);
  }
}

// ---------------------------------------------------------------------------
// Layer-2 aggregation (32 ch bf16) FUSED with the FC head:
// agg2row = dinv[n]*(ht2[n] + sum ht2[s]);  h = relu(agg2row + b2);
// t = relu(h @ fc_w + fc_b);  out[n] = t @ out_w + out_b.
// Wave per node: 4 edge-slots x 16 lanes on the gather; after xor-reduce
// every lane holds the full 32-ch row (2 ch each on cp=lane&15, replicated).
// Head: shuffle-broadcast h, 32-FMA matvec vs LDS fc_w, xor-reduce logits.
// ---------------------------------------------------------------------------
__global__ __launch_bounds__(WG) void k_agg32h(const int* __restrict__ rowbeg,
                                               const int* __restrict__ rowend,
                                               const int* __restrict__ perm,
                                               const float* __restrict__ dinv,
                                               const uint32* __restrict__ ht,
                                               const float* __restrict__ b2,
                                               const float* __restrict__ fc_w,
                                               const float* __restrict__ fc_b,
                                               const float* __restrict__ out_w,
                                               const float* __restrict__ out_b,
                                               float* __restrict__ out, int N) {
  __shared__ float fcs[32 * 32];
  __shared__ float b2s[32], fcbs[32], ows[64];
  const int tid = threadIdx.x;
  ((float4*)fcs)[tid] = ((const float4*)fc_w)[tid];  // 256 f4 = 1024 floats
  if (tid < 32) { b2s[tid] = b2[tid]; fcbs[tid] = fc_b[tid]; }
  if (tid < 64) ows[tid] = out_w[tid];
  __syncthreads();

  const int n = blockIdx.x * 4 + (tid >> 6);
  if (n >= N) return;
  const int lane = tid & 63;
  const int sub = lane >> 4;   // 0..3: which edge of the quad
  const int cp = lane & 15;    // channel-pair
  int beg = rowbeg[n], end = rowend[n];
  float a0 = 0.f, a1 = 0.f;
  if (sub == 0) {  // self-loop term
    uint32 v = ht[(size_t)n * 16 + cp];
    a0 += bflo(v); a1 += bfhi(v);
  }
  int j = beg;
  for (; j + 16 <= end; j += 16) {  // 16 edges per iteration
    int s[4];
    uint32 v[4];
#pragma unroll
    for (int u = 0; u < 4; u++) s[u] = perm[j + 4 * u + sub];
#pragma unroll
    for (int u = 0; u < 4; u++) v[u] = ht[(size_t)s[u] * 16 + cp];
#pragma unroll
    for (int u = 0; u < 4; u++) { a0 += bflo(v[u]); a1 += bfhi(v[u]); }
  }
  for (; j + 4 <= end; j += 4) {
    int s = perm[j + sub];
    uint32 v = ht[(size_t)s * 16 + cp];
    a0 += bflo(v); a1 += bfhi(v);
  }
  if (j + sub < end) {
    int s = perm[j + sub];
    uint32 v = ht[(size_t)s * 16 + cp];
    a0 += bflo(v); a1 += bfhi(v);
  }
  a0 += __shfl_xor(a0, 16, 64);
  a1 += __shfl_xor(a1, 16, 64);
  a0 += __shfl_xor(a0, 32, 64);
  a1 += __shfl_xor(a1, 32, 64);
  // every lane now holds the full sums for channels (2cp, 2cp+1)
  float dv = dinv[n];
  float hp0 = fmaxf(a0 * dv + b2s[2 * cp], 0.f);
  float hp1 = fmaxf(a1 * dv + b2s[2 * cp + 1], 0.f);

  // fc matvec: lane j (j = lane&31) computes acc_j = fcb[j] + sum_k h_k*fc[k][j]
  const int jj = lane & 31;
  float acc = fcbs[jj];
#pragma unroll
  for (int k = 0; k < 32; k++) {
    float hk = __shfl((k & 1) ? hp1 : hp0, k >> 1, 64);
    acc += hk * fcs[k * 32 + jj];
  }
  float t = fmaxf(acc, 0.f);
  float o0 = t * ows[2 * jj];
  float o1 = t * ows[2 * jj + 1];
#pragma unroll
  for (int off = 1; off <= 16; off <<= 1) {
    o0 += __shfl_xor(o0, off, 64);
    o1 += __shfl_xor(o1, off, 64);
  }
  if (lane == 0)
    ((float2*)out)[n] = make_float2(o0 + out_b[0], o1 + out_b[1]);
}

// ---------------------------------------------------------------------------
extern "C" void kernel_launch(void* const* d_in, const int* in_sizes, int n_in,
                              void* d_out, int out_size, void* d_ws, size_t ws_size,
                              hipStream_t stream) {
  const float* x   = (const float*)d_in[0];
  const int*   ei  = (const int*)d_in[1];
  const float* W1  = (const float*)d_in[2];
  const float* b1  = (const float*)d_in[3];
  const float* W2  = (const float*)d_in[4];
  const float* b2  = (const float*)d_in[5];
  const float* fcw = (const float*)d_in[6];
  const float* fcb = (const float*)d_in[7];
  const float* ow  = (const float*)d_in[8];
  const float* ob  = (const float*)d_in[9];

  const int N  = in_sizes[0] / 128;
  const int E  = in_sizes[1] / 2;
  const int NB = (N + BN - 1) / BN;        // buckets (<= NBMAX)
  const int NC = (E + CHUNK - 1) / CHUNK;  // chunks
  const int CAP = (int)(((long long)E * BN) / N) + 1024;  // bucket capacity

  // workspace: cursor(NB) | pairs(NB*CAP) | perm(NB*CAP) | rowbeg(N) |
  // rowend(N) | dinv(N) | ht1(32N u32) | agg1(64N f) | ht2(16N u32)
  char* p = (char*)d_ws;
  int* cursor = (int*)p;             p += ((size_t)NB + 16) * 4;
  p = (char*)(((uintptr_t)p + 63) & ~(uintptr_t)63);
  uint32* pairs = (uint32*)p;        p += (size_t)NB * CAP * 4 + 64;
  int* perm = (int*)p;               p += (size_t)NB * CAP * 4 + 64;
  int* rowbeg = (int*)p;             p += (size_t)N * 4 + 64;
  int* rowend = (int*)p;             p += (size_t)N * 4 + 64;
  float* dinv = (float*)p;           p += (size_t)N * 4 + 64;
  p = (char*)(((uintptr_t)p + 63) & ~(uintptr_t)63);
  uint32* ht1 = (uint32*)p;          p += (size_t)N * 32 * 4;
  float* agg1 = (float*)p;           p += (size_t)N * 64 * 4;
  uint32* ht2 = (uint32*)p;          p += (size_t)N * 16 * 4;
  float* out = (float*)d_out;

  hipMemsetAsync(cursor, 0, (size_t)NB * sizeof(int), stream);
  hipLaunchKernelGGL(k_bin, dim3(NC), dim3(WG), 0, stream,
                     ei, cursor, pairs, NB, E, CAP);
  hipLaunchKernelGGL(k_bsort, dim3(NB), dim3(WG), 0, stream,
                     pairs, cursor, perm, rowbeg, rowend, dinv, N, CAP);
  hipLaunchKernelGGL(k_gemm1, dim3((N + 63) / 64), dim3(WG), 0, stream,
                     x, W1, dinv, ht1, N);
  {
    long long tot = (long long)N * 64;
    hipLaunchKernelGGL(k_agg64b, dim3((int)((tot + WG - 1) / WG)), dim3(WG), 0,
                       stream, rowbeg, rowend, perm, dinv, ht1, agg1, N);
  }
  hipLaunchKernelGGL(k_gemm2, dim3((N + 63) / 64), dim3(WG), 0, stream,
                     agg1, b1, W2, dinv, ht2, N);
  hipLaunchKernelGGL(k_agg32h, dim3((N + 3) / 4), dim3(WG), 0, stream,
                     rowbeg, rowend, perm, dinv, ht2,
                     b2, fcw, fcb, ow, ob, out, N);
}

// Round 8
// 293.255 us; speedup vs baseline: 1.2675x; 1.0863x over previous
//
#include <hip/hip_runtime.h>

#define WG 256
#define BN 128        // nodes per bucket
#define NBMAX 800     // max buckets (N <= 102400)
#define CHUNK 4096    // edges per binning chunk

typedef unsigned int uint32;

__device__ inline ushort f2bf(float f) {  // fp32 -> bf16 RNE
  uint32 u = __float_as_uint(f);
  return (ushort)((u + 0x7fffu + ((u >> 16) & 1u)) >> 16);
}
__device__ inline float bflo(uint32 v) { return __uint_as_float(v << 16); }
__device__ inline float bfhi(uint32 v) { return __uint_as_float(v & 0xffff0000u); }

// int64 layout <=> all odd 32-bit words of the first 8 entries are zero.
__device__ inline bool detect_i64(const uint32* ei) {
  uint32 acc = 0;
#pragma unroll
  for (int i = 0; i < 8; i++) acc |= ei[2 * i + 1];
  return acc == 0u;
}

// ---------------------------------------------------------------------------
// Single-pass binning: per-chunk LDS histogram -> one global atomicAdd per
// (chunk,bucket) reserves a slice in [b*CAP,(b+1)*CAP) -> scatter packed
// (src<<7 | dst%BN). cursor[] pre-zeroed; afterwards cursor[b] = bucket count.
// ---------------------------------------------------------------------------
__global__ __launch_bounds__(WG) void k_bin(const int* __restrict__ ei,
                                            int* __restrict__ cursor,
                                            uint32* __restrict__ pairs,
                                            int NB, int E, int CAP) {
  __shared__ int hc[NBMAX];
  __shared__ int curs[NBMAX];
  const int c = blockIdx.x;
  for (int b = threadIdx.x; b < NB; b += WG) hc[b] = 0;
  __syncthreads();
  const bool i64 = detect_i64((const uint32*)ei);
  const int e0 = c * CHUNK;
  for (int i = 0; i < CHUNK; i += WG) {
    int e = e0 + i + threadIdx.x;
    if (e < E) {
      int d = i64 ? ei[2 * (E + e)] : ei[E + e];
      atomicAdd(&hc[d / BN], 1);
    }
  }
  __syncthreads();
  for (int b = threadIdx.x; b < NB; b += WG) {
    int cnt = hc[b];
    int base = 0;
    if (cnt > 0) base = atomicAdd(&cursor[b], cnt);
    curs[b] = b * CAP + base;
  }
  __syncthreads();
  for (int i = 0; i < CHUNK; i += WG) {
    int e = e0 + i + threadIdx.x;
    if (e < E) {
      int s, d;
      if (i64) { s = ei[2 * e]; d = ei[2 * (E + e)]; }
      else     { s = ei[e];     d = ei[E + e]; }
      int b = d / BN;
      int pos = atomicAdd(&curs[b], 1);
      if (pos < (b + 1) * CAP)  // overflow guard (never triggers w/ margin)
        pairs[pos] = ((uint32)s << 7) | (uint32)(d & (BN - 1));
    }
  }
}

// ---------------------------------------------------------------------------
// Per-bucket counting sort: packed pairs -> perm (grouped per dst node),
// rowbeg/rowend, dinv. Cursors in LDS; writes contiguous per block.
// ---------------------------------------------------------------------------
__global__ __launch_bounds__(WG) void k_bsort(const uint32* __restrict__ pairs,
                                              const int* __restrict__ cursor,
                                              int* __restrict__ perm,
                                              int* __restrict__ rowbeg,
                                              int* __restrict__ rowend,
                                              float* __restrict__ dinv,
                                              int N, int CAP) {
  __shared__ int cnt[BN];
  __shared__ int cur[BN];
  __shared__ int sc[BN];
  const int b = blockIdx.x;
  const int t = threadIdx.x;
  if (t < BN) cnt[t] = 0;
  __syncthreads();
  const int beg = b * CAP;
  int cb = cursor[b];
  const int end = beg + (cb < CAP ? cb : CAP);
  for (int e = beg + t; e < end; e += WG)
    atomicAdd(&cnt[pairs[e] & (BN - 1)], 1);
  __syncthreads();
  if (t < BN) sc[t] = cnt[t];
  __syncthreads();
  for (int off = 1; off < BN; off <<= 1) {
    int v = (t < BN && t >= off) ? sc[t - off] : 0;
    __syncthreads();
    if (t < BN) sc[t] += v;
    __syncthreads();
  }
  if (t < BN) {
    int excl = beg + sc[t] - cnt[t];
    cur[t] = excl;
    int n = b * BN + t;
    if (n < N) {
      rowbeg[n] = excl;
      rowend[n] = excl + cnt[t];
      dinv[n] = rsqrtf((float)(cnt[t] + 1));  // +1 = self-loop
    }
  }
  __syncthreads();
  for (int e = beg + t; e < end; e += WG) {
    uint32 p = pairs[e];
    int pos = atomicAdd(&cur[p & (BN - 1)], 1);
    perm[pos] = (int)(p >> 7);
  }
}

// ---------------------------------------------------------------------------
// GEMM1: ht1[n][64] = bf16( (x[n][128] @ W1[128][64]) * dinv[n] )
// ---------------------------------------------------------------------------
__global__ __launch_bounds__(WG) void k_gemm1(const float* __restrict__ x,
                                              const float* __restrict__ W1,
                                              const float* __restrict__ dinv,
                                              uint32* __restrict__ ht1, int N) {
  __shared__ float xs[64 * 128];
  __shared__ float w1s[128 * 64];
  const int tid = threadIdx.x;
  const int n0 = blockIdx.x * 64;

  for (int v = tid; v < 2048; v += WG)
    *(float4*)&w1s[v * 4] = ((const float4*)W1)[v];
  for (int v = tid; v < 2048; v += WG) {
    int row = v >> 5, c4 = v & 31;
    int n = n0 + row;
    float4 val = make_float4(0.f, 0.f, 0.f, 0.f);
    if (n < N) val = ((const float4*)x)[(size_t)n * 32 + c4];
    *(float4*)&xs[row * 128 + ((c4 ^ ((row >> 2) & 3)) << 2)] = val;
  }
  __syncthreads();

  const int cg = tid & 15;
  const int ng = tid >> 4;
  const int ngm = ng & 3;
  float acc[4][4] = {};

#pragma unroll 4
  for (int k4 = 0; k4 < 32; k4++) {
    float4 xa[4], wv[4];
#pragma unroll
    for (int i = 0; i < 4; i++)
      xa[i] = *(const float4*)&xs[(ng * 4 + i) * 128 + ((k4 ^ ngm) << 2)];
#pragma unroll
    for (int kk = 0; kk < 4; kk++)
      wv[kk] = *(const float4*)&w1s[(k4 * 4 + kk) * 64 + cg * 4];
#pragma unroll
    for (int i = 0; i < 4; i++) {
#pragma unroll
      for (int kk = 0; kk < 4; kk++) {
        float a = (kk == 0) ? xa[i].x : (kk == 1) ? xa[i].y : (kk == 2) ? xa[i].z : xa[i].w;
        acc[i][0] += a * wv[kk].x;
        acc[i][1] += a * wv[kk].y;
        acc[i][2] += a * wv[kk].z;
        acc[i][3] += a * wv[kk].w;
      }
    }
  }

#pragma unroll
  for (int i = 0; i < 4; i++) {
    int n = n0 + ng * 4 + i;
    if (n >= N) continue;
    float dv = dinv[n];
    uint32 u01 = ((uint32)f2bf(acc[i][1] * dv) << 16) | f2bf(acc[i][0] * dv);
    uint32 u23 = ((uint32)f2bf(acc[i][3] * dv) << 16) | f2bf(acc[i][2] * dv);
    ((uint2*)ht1)[(size_t)n * 16 + cg] = make_uint2(u01, u23);
  }
}

// ---------------------------------------------------------------------------
// CSR aggregation, 64 ch bf16: wave per node; 4 edges/step x uint2 (8B/lane);
// 16-edge unroll; fp32 accumulate; xor-shuffle reduce over edge slots.
// ---------------------------------------------------------------------------
__global__ __launch_bounds__(WG) void k_agg64b(const int* __restrict__ rowbeg,
                                               const int* __restrict__ rowend,
                                               const int* __restrict__ perm,
                                               const float* __restrict__ dinv,
                                               const uint32* __restrict__ ht,
                                               float* __restrict__ agg, int N) {
  int n = (blockIdx.x * WG + threadIdx.x) >> 6;
  int lane = threadIdx.x & 63;
  if (n >= N) return;
  const int sub = lane >> 4;   // edge slot 0..3
  const int cp = lane & 15;    // uint2 index within 128B row
  const uint2* __restrict__ tab = (const uint2*)ht;
  int beg = rowbeg[n], end = rowend[n];
  float a0 = 0.f, a1 = 0.f, a2 = 0.f, a3 = 0.f;
  if (sub == 0) {  // self-loop term
    uint2 v = tab[(size_t)n * 16 + cp];
    a0 += bflo(v.x); a1 += bfhi(v.x); a2 += bflo(v.y); a3 += bfhi(v.y);
  }
  int j = beg;
  for (; j + 16 <= end; j += 16) {  // 16 edges per iteration
    int s[4];
    uint2 v[4];
#pragma unroll
    for (int u = 0; u < 4; u++) s[u] = perm[j + 4 * u + sub];
#pragma unroll
    for (int u = 0; u < 4; u++) v[u] = tab[(size_t)s[u] * 16 + cp];
#pragma unroll
    for (int u = 0; u < 4; u++) {
      a0 += bflo(v[u].x); a1 += bfhi(v[u].x);
      a2 += bflo(v[u].y); a3 += bfhi(v[u].y);
    }
  }
  for (; j + 4 <= end; j += 4) {
    int s = perm[j + sub];
    uint2 v = tab[(size_t)s * 16 + cp];
    a0 += bflo(v.x); a1 += bfhi(v.x); a2 += bflo(v.y); a3 += bfhi(v.y);
  }
  if (j + sub < end) {
    int s = perm[j + sub];
    uint2 v = tab[(size_t)s * 16 + cp];
    a0 += bflo(v.x); a1 += bfhi(v.x); a2 += bflo(v.y); a3 += bfhi(v.y);
  }
  a0 += __shfl_xor(a0, 16, 64); a1 += __shfl_xor(a1, 16, 64);
  a2 += __shfl_xor(a2, 16, 64); a3 += __shfl_xor(a3, 16, 64);
  a0 += __shfl_xor(a0, 32, 64); a1 += __shfl_xor(a1, 32, 64);
  a2 += __shfl_xor(a2, 32, 64); a3 += __shfl_xor(a3, 32, 64);
  if (sub == 0) {
    float dv = dinv[n];
    ((float4*)agg)[(size_t)n * 16 + cp] =
        make_float4(a0 * dv, a1 * dv, a2 * dv, a3 * dv);
  }
}

// 32-ch bf16 variant: 8 edges/step x uint2 (64B row), 16-edge unroll.
__global__ __launch_bounds__(WG) void k_agg32b(const int* __restrict__ rowbeg,
                                               const int* __restrict__ rowend,
                                               const int* __restrict__ perm,
                                               const float* __restrict__ dinv,
                                               const uint32* __restrict__ ht,
                                               float* __restrict__ agg, int N) {
  int n = (blockIdx.x * WG + threadIdx.x) >> 6;
  int lane = threadIdx.x & 63;
  if (n >= N) return;
  const int sub = lane >> 3;   // edge slot 0..7
  const int cp = lane & 7;     // uint2 index within 64B row
  const uint2* __restrict__ tab = (const uint2*)ht;
  int beg = rowbeg[n], end = rowend[n];
  float a0 = 0.f, a1 = 0.f, a2 = 0.f, a3 = 0.f;
  if (sub == 0) {  // self-loop term
    uint2 v = tab[(size_t)n * 8 + cp];
    a0 += bflo(v.x); a1 += bfhi(v.x); a2 += bflo(v.y); a3 += bfhi(v.y);
  }
  int j = beg;
  for (; j + 16 <= end; j += 16) {  // 16 edges per iteration
    int s[2];
    uint2 v[2];
#pragma unroll
    for (int u = 0; u < 2; u++) s[u] = perm[j + 8 * u + sub];
#pragma unroll
    for (int u = 0; u < 2; u++) v[u] = tab[(size_t)s[u] * 8 + cp];
#pragma unroll
    for (int u = 0; u < 2; u++) {
      a0 += bflo(v[u].x); a1 += bfhi(v[u].x);
      a2 += bflo(v[u].y); a3 += bfhi(v[u].y);
    }
  }
  for (; j + 8 <= end; j += 8) {
    int s = perm[j + sub];
    uint2 v = tab[(size_t)s * 8 + cp];
    a0 += bflo(v.x); a1 += bfhi(v.x); a2 += bflo(v.y); a3 += bfhi(v.y);
  }
  if (j + sub < end) {
    int s = perm[j + sub];
    uint2 v = tab[(size_t)s * 8 + cp];
    a0 += bflo(v.x); a1 += bfhi(v.x); a2 += bflo(v.y); a3 += bfhi(v.y);
  }
  a0 += __shfl_xor(a0, 8, 64);  a1 += __shfl_xor(a1, 8, 64);
  a2 += __shfl_xor(a2, 8, 64);  a3 += __shfl_xor(a3, 8, 64);
  a0 += __shfl_xor(a0, 16, 64); a1 += __shfl_xor(a1, 16, 64);
  a2 += __shfl_xor(a2, 16, 64); a3 += __shfl_xor(a3, 16, 64);
  a0 += __shfl_xor(a0, 32, 64); a1 += __shfl_xor(a1, 32, 64);
  a2 += __shfl_xor(a2, 32, 64); a3 += __shfl_xor(a3, 32, 64);
  if (sub == 0) {
    float dv = dinv[n];
    ((float4*)agg)[(size_t)n * 8 + cp] =
        make_float4(a0 * dv, a1 * dv, a2 * dv, a3 * dv);
  }
}

// ---------------------------------------------------------------------------
// GEMM2: ht2[n][32] = bf16( (relu(agg1[n][64] + b1) @ W2[64][32]) * dinv[n] )
// ---------------------------------------------------------------------------
__global__ __launch_bounds__(WG) void k_gemm2(const float* __restrict__ agg1,
                                              const float* __restrict__ b1,
                                              const float* __restrict__ W2,
                                              const float* __restrict__ dinv,
                                              uint32* __restrict__ ht2, int N) {
  __shared__ float as[64 * 68];
  __shared__ float w2s[64 * 32];
  const int tid = threadIdx.x;
  const int n0 = blockIdx.x * 64;

  for (int v = tid; v < 512; v += WG)
    *(float4*)&w2s[v * 4] = ((const float4*)W2)[v];
  for (int v = tid; v < 1024; v += WG) {
    int row = v >> 4, c4 = v & 15;
    int n = n0 + row;
    float4 val = make_float4(0.f, 0.f, 0.f, 0.f);
    if (n < N) {
      float4 g = ((const float4*)agg1)[(size_t)n * 16 + c4];
      float4 bb = ((const float4*)b1)[c4];
      val.x = fmaxf(g.x + bb.x, 0.f);
      val.y = fmaxf(g.y + bb.y, 0.f);
      val.z = fmaxf(g.z + bb.z, 0.f);
      val.w = fmaxf(g.w + bb.w, 0.f);
    }
    *(float4*)&as[row * 68 + c4 * 4] = val;
  }
  __syncthreads();

  const int cg = tid & 15;
  const int ng = tid >> 4;
  float acc[4][2] = {};

#pragma unroll 4
  for (int k4 = 0; k4 < 16; k4++) {
    float4 xa[4];
    float2 wv[4];
#pragma unroll
    for (int i = 0; i < 4; i++)
      xa[i] = *(const float4*)&as[(ng * 4 + i) * 68 + k4 * 4];
#pragma unroll
    for (int kk = 0; kk < 4; kk++)
      wv[kk] = *(const float2*)&w2s[(k4 * 4 + kk) * 32 + cg * 2];
#pragma unroll
    for (int i = 0; i < 4; i++) {
#pragma unroll
      for (int kk = 0; kk < 4; kk++) {
        float a = (kk == 0) ? xa[i].x : (kk == 1) ? xa[i].y : (kk == 2) ? xa[i].z : xa[i].w;
        acc[i][0] += a * wv[kk].x;
        acc[i][1] += a * wv[kk].y;
      }
    }
  }

#pragma unroll
  for (int i = 0; i < 4; i++) {
    int n = n0 + ng * 4 + i;
    if (n >= N) continue;
    float dv = dinv[n];
    ht2[(size_t)n * 16 + cg] =
        ((uint32)f2bf(acc[i][1] * dv) << 16) | f2bf(acc[i][0] * dv);
  }
}

// ---------------------------------------------------------------------------
// Final head: out[n][2] = (relu(relu(agg2[n]+b2) @ fc_w + fc_b)) @ out_w + out_b
// ---------------------------------------------------------------------------
__global__ __launch_bounds__(WG) void k_final(const float* __restrict__ agg2,
                                              const float* __restrict__ b2,
                                              const float* __restrict__ fc_w,
                                              const float* __restrict__ fc_b,
                                              const float* __restrict__ out_w,
                                              const float* __restrict__ out_b,
                                              float* __restrict__ out, int N) {
  __shared__ float hs[256 * 33];
  __shared__ float fcs[32 * 32];
  __shared__ float b2s[32], fcbs[32], ows[64];
  const int tid = threadIdx.x;
  const int n0 = blockIdx.x * 256;

  ((float4*)fcs)[tid] = ((const float4*)fc_w)[tid];
  if (tid < 32) {
    b2s[tid] = b2[tid];
    fcbs[tid] = fc_b[tid];
  }
  if (tid < 64) ows[tid] = out_w[tid];
  for (int v = tid; v < 2048; v += WG) {
    int row = v >> 3, c4 = v & 7;
    int n = n0 + row;
    float4 val = make_float4(0.f, 0.f, 0.f, 0.f);
    if (n < N) val = ((const float4*)agg2)[(size_t)n * 8 + c4];
    float* p = &hs[row * 33 + c4 * 4];
    p[0] = val.x; p[1] = val.y; p[2] = val.z; p[3] = val.w;
  }
  __syncthreads();

  int n = n0 + tid;
  float acc[32] = {};
  const int base = tid * 33;
#pragma unroll
  for (int k = 0; k < 32; k++) {
    float vk = fmaxf(hs[base + k] + b2s[k], 0.f);
#pragma unroll
    for (int j4 = 0; j4 < 8; j4++) {
      float4 f = *(const float4*)&fcs[k * 32 + j4 * 4];
      acc[j4 * 4 + 0] += vk * f.x;
      acc[j4 * 4 + 1] += vk * f.y;
      acc[j4 * 4 + 2] += vk * f.z;
      acc[j4 * 4 + 3] += vk * f.w;
    }
  }
  float o0 = out_b[0], o1 = out_b[1];
#pragma unroll
  for (int j = 0; j < 32; j++) {
    float t = fmaxf(acc[j] + fcbs[j], 0.f);
    o0 += t * ows[2 * j];
    o1 += t * ows[2 * j + 1];
  }
  if (n < N) ((float2*)out)[n] = make_float2(o0, o1);
}

// ---------------------------------------------------------------------------
extern "C" void kernel_launch(void* const* d_in, const int* in_sizes, int n_in,
                              void* d_out, int out_size, void* d_ws, size_t ws_size,
                              hipStream_t stream) {
  const float* x   = (const float*)d_in[0];
  const int*   ei  = (const int*)d_in[1];
  const float* W1  = (const float*)d_in[2];
  const float* b1  = (const float*)d_in[3];
  const float* W2  = (const float*)d_in[4];
  const float* b2  = (const float*)d_in[5];
  const float* fcw = (const float*)d_in[6];
  const float* fcb = (const float*)d_in[7];
  const float* ow  = (const float*)d_in[8];
  const float* ob  = (const float*)d_in[9];

  const int N  = in_sizes[0] / 128;
  const int E  = in_sizes[1] / 2;
  const int NB = (N + BN - 1) / BN;        // buckets (<= NBMAX)
  const int NC = (E + CHUNK - 1) / CHUNK;  // chunks
  const int CAP = (int)(((long long)E * BN) / N) + 1024;  // bucket capacity

  // workspace: cursor(NB) | pairs(NB*CAP) [agg2 aliases: dead after bsort] |
  // perm(NB*CAP) | rowbeg(N) | rowend(N) | dinv(N) | ht1(32N u32) |
  // agg1(64N f) | ht2(16N u32)
  char* p = (char*)d_ws;
  int* cursor = (int*)p;             p += ((size_t)NB + 16) * 4;
  p = (char*)(((uintptr_t)p + 63) & ~(uintptr_t)63);
  uint32* pairs = (uint32*)p;
  float* agg2 = (float*)p;           p += (size_t)NB * CAP * 4 + 64;
  int* perm = (int*)p;               p += (size_t)NB * CAP * 4 + 64;
  int* rowbeg = (int*)p;             p += (size_t)N * 4 + 64;
  int* rowend = (int*)p;             p += (size_t)N * 4 + 64;
  float* dinv = (float*)p;           p += (size_t)N * 4 + 64;
  p = (char*)(((uintptr_t)p + 63) & ~(uintptr_t)63);
  uint32* ht1 = (uint32*)p;          p += (size_t)N * 32 * 4;
  float* agg1 = (float*)p;           p += (size_t)N * 64 * 4;
  uint32* ht2 = (uint32*)p;          p += (size_t)N * 16 * 4;
  float* out = (float*)d_out;

  hipMemsetAsync(cursor, 0, (size_t)NB * sizeof(int), stream);
  hipLaunchKernelGGL(k_bin, dim3(NC), dim3(WG), 0, stream,
                     ei, cursor, pairs, NB, E, CAP);
  hipLaunchKernelGGL(k_bsort, dim3(NB), dim3(WG), 0, stream,
                     pairs, cursor, perm, rowbeg, rowend, dinv, N, CAP);
  hipLaunchKernelGGL(k_gemm1, dim3((N + 63) / 64), dim3(WG), 0, stream,
                     x, W1, dinv, ht1, N);
  {
    long long tot = (long long)N * 64;
    hipLaunchKernelGGL(k_agg64b, dim3((int)((tot + WG - 1) / WG)), dim3(WG), 0,
                       stream, rowbeg, rowend, perm, dinv, ht1, agg1, N);
  }
  hipLaunchKernelGGL(k_gemm2, dim3((N + 63) / 64), dim3(WG), 0, stream,
                     agg1, b1, W2, dinv, ht2, N);
  {
    long long tot = (long long)N * 64;
    hipLaunchKernelGGL(k_agg32b, dim3((int)((tot + WG - 1) / WG)), dim3(WG), 0,
                       stream, rowbeg, rowend, perm, dinv, ht2, agg2, N);
  }
  hipLaunchKernelGGL(k_final, dim3((N + 255) / 256), dim3(WG), 0, stream,
                     agg2, b2, fcw, fcb, ow, ob, out, N);
}